// Round 1
// baseline (595.108 us; speedup 1.0000x reference)
//
#include <hip/hip_runtime.h>
#include <math.h>

#define NB 8
#define CC 14
#define HH 512
#define WW 512
#define HW (HH*WW)          // 262144
#define NHW (NB*HW)         // 2097152
#define NSPLIT 8
#define CHUNK (HW/NSPLIT)   // 32768

// ---------------- Stage A: teacher argmax -> uint8 gray map ----------------
__global__ __launch_bounds__(256) void k_argmax(const float* __restrict__ T,
                                                unsigned char* __restrict__ tmap) {
    int i = blockIdx.x * blockDim.x + threadIdx.x;
    if (i >= NHW) return;
    int n = i / HW;
    int p = i - n * HW;
    const float* base = T + (size_t)n * CC * HW + p;
    float best = base[0];
    int bi = 0;
#pragma unroll
    for (int c = 1; c < CC; ++c) {
        float v = base[(size_t)c * HW];
        if (v > best) { best = v; bi = c; }
    }
    float g = ((float)bi / 13.0f) * 255.0f;   // match op order: /13 then *255
    tmap[i] = (unsigned char)g;               // truncating cast
}

// ---------------- Stage B1: Sobel (replicate border) -> mag + sector -------
__global__ __launch_bounds__(256) void k_sobel(const unsigned char* __restrict__ tmap,
                                               float* __restrict__ mag,
                                               unsigned char* __restrict__ sect) {
    int i = blockIdx.x * blockDim.x + threadIdx.x;
    if (i >= NHW) return;
    int n = i / HW;
    int p = i - n * HW;
    int y = p / WW;
    int x = p - y * WW;
    const unsigned char* im = tmap + (size_t)n * HW;
    int ym = y > 0 ? y - 1 : 0, yp = y < HH - 1 ? y + 1 : HH - 1;
    int xm = x > 0 ? x - 1 : 0, xp = x < WW - 1 ? x + 1 : WW - 1;
    int a00 = im[ym * WW + xm], a01 = im[ym * WW + x], a02 = im[ym * WW + xp];
    int a10 = im[y  * WW + xm],                        a12 = im[y  * WW + xp];
    int a20 = im[yp * WW + xm], a21 = im[yp * WW + x], a22 = im[yp * WW + xp];
    int gx = (a02 - a00) + 2 * (a12 - a10) + (a22 - a20);
    int gy = (a20 - a00) + 2 * (a21 - a01) + (a22 - a02);
    int m = (gx < 0 ? -gx : gx) + (gy < 0 ? -gy : gy);   // L1 magnitude, exact int
    float ang = atan2f((float)gy, (float)gx) * 57.29577951308232f; // degrees
    ang = fmodf(ang, 180.0f);
    if (ang < 0.0f) ang += 180.0f;
    int s;
    if (ang < 22.5f || ang >= 157.5f) s = 0;
    else if (ang < 67.5f)             s = 1;
    else if (ang < 112.5f)            s = 2;
    else                              s = 3;
    mag[i] = (float)m;
    sect[i] = (unsigned char)s;
}

// ---------------- Stage B2: NMS (zero-padded shifts) -> weak/strong --------
__global__ __launch_bounds__(256) void k_nms(const float* __restrict__ mag,
                                             const unsigned char* __restrict__ sect,
                                             unsigned char* __restrict__ weak,
                                             unsigned char* __restrict__ strong) {
    int i = blockIdx.x * blockDim.x + threadIdx.x;
    if (i >= NHW) return;
    int n = i / HW;
    int p = i - n * HW;
    int y = p / WW;
    int x = p - y * WW;
    const float* m = mag + (size_t)n * HW;
    float mc = m[p];
    int s = sect[i];
    int dy1, dx1, dy2, dx2;
    if (s == 0)      { dy1 = 0;  dx1 = 1;  dy2 = 0; dx2 = -1; }
    else if (s == 1) { dy1 = -1; dx1 = 1;  dy2 = 1; dx2 = -1; }
    else if (s == 2) { dy1 = -1; dx1 = 0;  dy2 = 1; dx2 = 0;  }
    else             { dy1 = -1; dx1 = -1; dy2 = 1; dx2 = 1;  }
    int y1 = y + dy1, x1 = x + dx1, y2 = y + dy2, x2 = x + dx2;
    float n1 = (y1 < 0 || y1 >= HH || x1 < 0 || x1 >= WW) ? 0.0f : m[y1 * WW + x1];
    float n2 = (y2 < 0 || y2 >= HH || x2 < 0 || x2 >= WW) ? 0.0f : m[y2 * WW + x2];
    float nms = (mc >= n1 && mc >= n2) ? mc : 0.0f;
    weak[i]   = (nms > 10.0f) ? 1 : 0;
    strong[i] = (nms > 50.0f) ? 1 : 0;
}

// ---------------- Stage C: one hysteresis iteration ------------------------
__global__ __launch_bounds__(256) void k_hyst(const unsigned char* __restrict__ src,
                                              const unsigned char* __restrict__ weak,
                                              unsigned char* __restrict__ dst) {
    int i = blockIdx.x * blockDim.x + threadIdx.x;
    if (i >= NHW) return;
    int n = i / HW;
    int p = i - n * HW;
    int y = p / WW;
    int x = p - y * WW;
    const unsigned char* s = src + (size_t)n * HW;
    int any = 0;
    int y0 = y > 0 ? y - 1 : 0, y1 = y < HH - 1 ? y + 1 : HH - 1;
    int x0 = x > 0 ? x - 1 : 0, x1 = x < WW - 1 ? x + 1 : WW - 1;
    for (int yy = y0; yy <= y1; ++yy)
        for (int xx = x0; xx <= x1; ++xx)
            any |= s[yy * WW + xx];
    dst[i] = (any && weak[i]) ? 1 : 0;
}

// ---------------- Stage D: 10x10 dilate, separable (window [-5,+4]) --------
__global__ __launch_bounds__(256) void k_dilrow(const unsigned char* __restrict__ src,
                                                unsigned char* __restrict__ dst) {
    int i = blockIdx.x * blockDim.x + threadIdx.x;
    if (i >= NHW) return;
    int n = i / HW;
    int p = i - n * HW;
    int y = p / WW;
    int x = p - y * WW;
    const unsigned char* s = src + (size_t)n * HW + y * WW;
    int any = 0;
    int x0 = x - 5 > 0 ? x - 5 : 0;
    int x1 = x + 4 < WW - 1 ? x + 4 : WW - 1;
    for (int xx = x0; xx <= x1; ++xx) any |= s[xx];
    dst[i] = (unsigned char)(any ? 1 : 0);
}

__global__ __launch_bounds__(256) void k_dilcol(const unsigned char* __restrict__ src,
                                                unsigned char* __restrict__ dst) {
    int i = blockIdx.x * blockDim.x + threadIdx.x;
    if (i >= NHW) return;
    int n = i / HW;
    int p = i - n * HW;
    int y = p / WW;
    int x = p - y * WW;
    const unsigned char* s = src + (size_t)n * HW;
    int any = 0;
    int y0 = y - 5 > 0 ? y - 5 : 0;
    int y1 = y + 4 < HH - 1 ? y + 4 : HH - 1;
    for (int yy = y0; yy <= y1; ++yy) any |= s[yy * WW + x];
    dst[i] = (unsigned char)(any ? 1 : 0);
}

// ---------------- Stage E: 10x10 box blur, reflect101, separable -----------
__global__ __launch_bounds__(256) void k_blurrow(const unsigned char* __restrict__ d,
                                                 float* __restrict__ rowsum) {
    int i = blockIdx.x * blockDim.x + threadIdx.x;
    if (i >= NHW) return;
    int n = i / HW;
    int p = i - n * HW;
    int y = p / WW;
    int x = p - y * WW;
    const unsigned char* s = d + (size_t)n * HW + y * WW;
    int cnt = 0;
    for (int dx = -5; dx <= 4; ++dx) {
        int xx = x + dx;
        xx = xx < 0 ? -xx : (xx >= WW ? 2 * WW - 2 - xx : xx);  // reflect101
        cnt += s[xx];
    }
    rowsum[i] = (float)cnt;
}

__global__ __launch_bounds__(256) void k_blurcol(const float* __restrict__ rowsum,
                                                 float* __restrict__ e) {
    int i = blockIdx.x * blockDim.x + threadIdx.x;
    if (i >= NHW) return;
    int n = i / HW;
    int p = i - n * HW;
    int y = p / WW;
    int x = p - y * WW;
    const float* s = rowsum + (size_t)n * HW;
    float cnt = 0.0f;
    for (int dy = -5; dy <= 4; ++dy) {
        int yy = y + dy;
        yy = yy < 0 ? -yy : (yy >= HH ? 2 * HH - 2 - yy : yy);  // reflect101
        cnt += s[yy * WW + x];
    }
    float b = (255.0f * cnt) / 100.0f;   // exact: sum of 255-valued pixels / 100
    b = rintf(b);                        // round half to even, matches jnp.round
    e[i] = b / 255.0f;
}

// ---------------- Stage F: per-(n,c) online-softmax KL partials ------------
// state per channel: (Mt, Zt, Wt, Ms, Zs) with
//   Zt = sum exp(a - Mt), Wt = sum exp(a - Mt)*(a - b), Zs = sum exp(b - Ms)
// loss_nc = Wt/Zt - (Mt + log Zt) + (Ms + log Zs)
__global__ __launch_bounds__(256) void k_kl_partial(const float* __restrict__ S,
                                                    const float* __restrict__ T,
                                                    const float* __restrict__ E,
                                                    double* __restrict__ partial) {
    int cidx  = blockIdx.x;   // 0..111 (n*CC + c)
    int split = blockIdx.y;   // 0..NSPLIT-1
    int n = cidx / CC;
    const float* Tp = T + (size_t)cidx * HW + (size_t)split * CHUNK;
    const float* Sp = S + (size_t)cidx * HW + (size_t)split * CHUNK;
    const float* Ep = E + (size_t)n * HW + (size_t)split * CHUNK;

    float Mt = -INFINITY, Ms = -INFINITY;
    double Zt = 0.0, Wt = 0.0, Zs = 0.0;
    for (int j = threadIdx.x; j < CHUNK; j += 256) {
        float e = Ep[j];
        float t = e * Tp[j];
        float s = e * Sp[j];
        float d = t - s;
        if (t > Mt) {
            float sc = expf(Mt - t);           // exp(-inf)=0 on first hit
            Zt = Zt * (double)sc + 1.0;
            Wt = Wt * (double)sc + (double)d;
            Mt = t;
        } else {
            float pr = expf(t - Mt);
            Zt += (double)pr;
            Wt += (double)pr * (double)d;
        }
        if (s > Ms) {
            float sc = expf(Ms - s);
            Zs = Zs * (double)sc + 1.0;
            Ms = s;
        } else {
            Zs += (double)expf(s - Ms);
        }
    }

    __shared__ float  sMt[256], sMs[256];
    __shared__ double sZt[256], sWt[256], sZs[256];
    int tid = threadIdx.x;
    sMt[tid] = Mt; sMs[tid] = Ms; sZt[tid] = Zt; sWt[tid] = Wt; sZs[tid] = Zs;
    __syncthreads();
    for (int off = 128; off > 0; off >>= 1) {
        if (tid < off) {
            // t-state combine
            float M1 = sMt[tid], M2 = sMt[tid + off];
            float Mn = fmaxf(M1, M2);
            double e1 = exp((double)(M1 - Mn)), e2 = exp((double)(M2 - Mn));
            sZt[tid] = sZt[tid] * e1 + sZt[tid + off] * e2;
            sWt[tid] = sWt[tid] * e1 + sWt[tid + off] * e2;
            sMt[tid] = Mn;
            // s-state combine
            float N1 = sMs[tid], N2 = sMs[tid + off];
            float Nn = fmaxf(N1, N2);
            double f1 = exp((double)(N1 - Nn)), f2 = exp((double)(N2 - Nn));
            sZs[tid] = sZs[tid] * f1 + sZs[tid + off] * f2;
            sMs[tid] = Nn;
        }
        __syncthreads();
    }
    if (tid == 0) {
        double* out = partial + ((size_t)cidx * NSPLIT + split) * 5;
        out[0] = (double)sMt[0];
        out[1] = sZt[0];
        out[2] = sWt[0];
        out[3] = (double)sMs[0];
        out[4] = sZs[0];
    }
}

// ---------------- Stage G: final reduce -> scalar loss ---------------------
__global__ __launch_bounds__(128) void k_kl_final(const double* __restrict__ partial,
                                                  float* __restrict__ out) {
    int tid = threadIdx.x;
    double loss = 0.0;
    if (tid < NB * CC) {
        double Mt = -INFINITY, Zt = 0.0, Wt = 0.0, Ms = -INFINITY, Zs = 0.0;
        for (int sp = 0; sp < NSPLIT; ++sp) {
            const double* p = partial + ((size_t)tid * NSPLIT + sp) * 5;
            double M2 = p[0], Z2 = p[1], W2 = p[2];
            double Mn = fmax(Mt, M2);
            double e1 = exp(Mt - Mn), e2 = exp(M2 - Mn); // exp(-inf)=0 first time
            Zt = Zt * e1 + Z2 * e2;
            Wt = Wt * e1 + W2 * e2;
            Mt = Mn;
            double N2 = p[3], Y2 = p[4];
            double Nn = fmax(Ms, N2);
            double f1 = exp(Ms - Nn), f2 = exp(N2 - Nn);
            Zs = Zs * f1 + Y2 * f2;
            Ms = Nn;
        }
        loss = Wt / Zt - Mt - log(Zt) + Ms + log(Zs);
    }
    __shared__ double red[128];
    red[tid] = loss;
    __syncthreads();
    for (int off = 64; off > 0; off >>= 1) {
        if (tid < off) red[tid] += red[tid + off];
        __syncthreads();
    }
    if (tid == 0) out[0] = (float)(red[0] / (double)(NB * CC));  // T^2 = 1
}

extern "C" void kernel_launch(void* const* d_in, const int* in_sizes, int n_in,
                              void* d_out, int out_size, void* d_ws, size_t ws_size,
                              hipStream_t stream) {
    const float* S = (const float*)d_in[0];   // preds_S
    const float* T = (const float*)d_in[1];   // preds_T
    float* out = (float*)d_out;

    char* ws = (char*)d_ws;
    float*         e_buf   = (float*)(ws);                              // 8 MB
    float*         f_buf   = (float*)(ws + (size_t)NHW * 4);            // 8 MB (mag -> rowsum)
    unsigned char* tmap    = (unsigned char*)(ws + (size_t)NHW * 8);    // 2 MB (tmap -> dilated)
    unsigned char* sect    = (unsigned char*)(ws + (size_t)NHW * 9);    // 2 MB (sector -> rowany)
    unsigned char* weak    = (unsigned char*)(ws + (size_t)NHW * 10);   // 2 MB
    unsigned char* sA      = (unsigned char*)(ws + (size_t)NHW * 11);   // 2 MB
    unsigned char* sB      = (unsigned char*)(ws + (size_t)NHW * 12);   // 2 MB
    double*        partial = (double*)(ws + (size_t)NHW * 13);          // 35840 B

    dim3 blk(256);
    dim3 grd(NHW / 256);

    k_argmax<<<grd, blk, 0, stream>>>(T, tmap);
    k_sobel <<<grd, blk, 0, stream>>>(tmap, f_buf, sect);
    k_nms   <<<grd, blk, 0, stream>>>(f_buf, sect, weak, sA);

    for (int it = 0; it < 16; ++it) {
        const unsigned char* src = (it & 1) ? sB : sA;
        unsigned char*       dst = (it & 1) ? sA : sB;
        k_hyst<<<grd, blk, 0, stream>>>(src, weak, dst);
    }
    // 16 iterations -> final strong lands back in sA

    k_dilrow <<<grd, blk, 0, stream>>>(sA, sect);     // reuse sector buf
    k_dilcol <<<grd, blk, 0, stream>>>(sect, tmap);   // reuse tmap buf as dilated
    k_blurrow<<<grd, blk, 0, stream>>>(tmap, f_buf);  // reuse mag buf as rowsum
    k_blurcol<<<grd, blk, 0, stream>>>(f_buf, e_buf);

    dim3 kgrd(NB * CC, NSPLIT);
    k_kl_partial<<<kgrd, blk, 0, stream>>>(S, T, e_buf, partial);
    k_kl_final<<<1, 128, 0, stream>>>(partial, out);
    (void)in_sizes; (void)n_in; (void)out_size; (void)ws_size;
}

// Round 2
// 352.258 us; speedup vs baseline: 1.6894x; 1.6894x over previous
//
#include <hip/hip_runtime.h>
#include <math.h>

#define NB 8
#define CC 14
#define HH 512
#define WW 512
#define HW (HH*WW)          // 262144
#define NHW (NB*HW)         // 2097152
#define WPR 8               // uint64 words per row (512 bits)
#define WPI (HH*WPR)        // 4096 words per image
#define KSPLIT 16
#define KCHUNK (HW/KSPLIT)  // 16384

typedef unsigned long long u64;

// ---------------- Stage A: teacher argmax -> uint8 gray map ----------------
__global__ __launch_bounds__(256) void k_argmax(const float* __restrict__ T,
                                                unsigned char* __restrict__ tmap) {
    int i = blockIdx.x * blockDim.x + threadIdx.x;
    if (i >= NHW) return;
    int n = i / HW;
    int p = i - n * HW;
    const float* base = T + (size_t)n * CC * HW + p;
    float best = base[0];
    int bi = 0;
#pragma unroll
    for (int c = 1; c < CC; ++c) {
        float v = base[(size_t)c * HW];
        if (v > best) { best = v; bi = c; }
    }
    float g = ((float)bi / 13.0f) * 255.0f;   // match op order: /13 then *255
    tmap[i] = (unsigned char)g;               // truncating cast
}

// ------- Stage B1: Sobel (replicate border) -> packed (mag<<2)|sector ------
__global__ __launch_bounds__(256) void k_sobel(const unsigned char* __restrict__ tmap,
                                               unsigned short* __restrict__ m16) {
    int i = blockIdx.x * blockDim.x + threadIdx.x;
    if (i >= NHW) return;
    int n = i / HW;
    int p = i - n * HW;
    int y = p / WW;
    int x = p - y * WW;
    const unsigned char* im = tmap + (size_t)n * HW;
    int ym = y > 0 ? y - 1 : 0, yp = y < HH - 1 ? y + 1 : HH - 1;
    int xm = x > 0 ? x - 1 : 0, xp = x < WW - 1 ? x + 1 : WW - 1;
    int a00 = im[ym * WW + xm], a01 = im[ym * WW + x], a02 = im[ym * WW + xp];
    int a10 = im[y  * WW + xm],                        a12 = im[y  * WW + xp];
    int a20 = im[yp * WW + xm], a21 = im[yp * WW + x], a22 = im[yp * WW + xp];
    int gx = (a02 - a00) + 2 * (a12 - a10) + (a22 - a20);
    int gy = (a20 - a00) + 2 * (a21 - a01) + (a22 - a02);
    int m = (gx < 0 ? -gx : gx) + (gy < 0 ? -gy : gy);   // L1 magnitude, exact int
    float ang = atan2f((float)gy, (float)gx) * 57.29577951308232f; // degrees
    ang = fmodf(ang, 180.0f);
    if (ang < 0.0f) ang += 180.0f;
    int s;
    if (ang < 22.5f || ang >= 157.5f) s = 0;
    else if (ang < 67.5f)             s = 1;
    else if (ang < 112.5f)            s = 2;
    else                              s = 3;
    m16[i] = (unsigned short)((m << 2) | s);
}

// ------- Stage B2: NMS (zero-pad shifts) -> bit-packed weak/strong ---------
__global__ __launch_bounds__(256) void k_nms(const unsigned short* __restrict__ m16,
                                             u64* __restrict__ weakBits,
                                             u64* __restrict__ strongBits) {
    int i = blockIdx.x * blockDim.x + threadIdx.x;
    int n = i / HW;
    int p = i - n * HW;
    int y = p / WW;
    int x = p - y * WW;
    const unsigned short* mp = m16 + (size_t)n * HW;
    int v = mp[p];
    int mc = v >> 2;
    int s = v & 3;
    int dy1, dx1, dy2, dx2;
    if (s == 0)      { dy1 = 0;  dx1 = 1;  dy2 = 0; dx2 = -1; }
    else if (s == 1) { dy1 = -1; dx1 = 1;  dy2 = 1; dx2 = -1; }
    else if (s == 2) { dy1 = -1; dx1 = 0;  dy2 = 1; dx2 = 0;  }
    else             { dy1 = -1; dx1 = -1; dy2 = 1; dx2 = 1;  }
    int y1 = y + dy1, x1 = x + dx1, y2 = y + dy2, x2 = x + dx2;
    int n1 = (y1 < 0 || y1 >= HH || x1 < 0 || x1 >= WW) ? 0 : (mp[y1 * WW + x1] >> 2);
    int n2 = (y2 < 0 || y2 >= HH || x2 < 0 || x2 >= WW) ? 0 : (mp[y2 * WW + x2] >> 2);
    int nms = (mc >= n1 && mc >= n2) ? mc : 0;
    u64 wm = __ballot(nms > 10);
    u64 sm = __ballot(nms > 50);
    if ((threadIdx.x & 63) == 0) {
        weakBits[i >> 6]   = wm;
        strongBits[i >> 6] = sm;
    }
}

// ---- Stage C+D: 16 hysteresis iterations + 10x10 dilate, bit-packed -------
// 2 blocks per image (top/bottom 256 rows), 21-row halo: 16 grow iters
// contaminate 16 rows from the unknown tile edge, dilate needs 5 more -> exact.
#define HALO 21
#define TROWS (256 + 2*HALO)   // 298
__global__ __launch_bounds__(1024) void k_hyst_dil(const u64* __restrict__ strongBits,
                                                   const u64* __restrict__ weakBits,
                                                   u64* __restrict__ dilBits) {
    int blk  = blockIdx.x;
    int n    = blk >> 1;
    int half = blk & 1;
    int g0   = half * 256 - HALO;          // virtual first row of tile
    __shared__ u64 A[TROWS * WPR];
    __shared__ u64 B[TROWS * WPR];
    __shared__ u64 Wl[TROWS * WPR];
    int tid = threadIdx.x;

    for (int idx = tid; idx < TROWS * WPR; idx += 1024) {
        int vr = g0 + (idx >> 3);
        int w  = idx & 7;
        u64 sv = 0, wv = 0;
        if (vr >= 0 && vr < HH) {
            sv = strongBits[(size_t)n * WPI + vr * WPR + w];
            wv = weakBits  [(size_t)n * WPI + vr * WPR + w];
        }
        A[idx] = sv;
        Wl[idx] = wv;
    }
    __syncthreads();

    for (int it = 0; it < 16; ++it) {
        const u64* src = (it & 1) ? B : A;
        u64*       dst = (it & 1) ? A : B;
        for (int idx = tid; idx < TROWS * WPR; idx += 1024) {
            int r = idx >> 3;
            int w = idx & 7;
            u64 c  = src[idx];
            u64 up = (r > 0)         ? src[idx - 8] : 0;
            u64 dn = (r < TROWS - 1) ? src[idx + 8] : 0;
            u64 a = c | up | dn;
            u64 pL = 0, pR = 0;
            if (w > 0) {
                u64 cl = src[idx - 1];
                u64 ul = (r > 0)         ? src[idx - 9] : 0;
                u64 dl = (r < TROWS - 1) ? src[idx + 7] : 0;
                pL = cl | ul | dl;
            }
            if (w < 7) {
                u64 cr = src[idx + 1];
                u64 ur = (r > 0)         ? src[idx - 7] : 0;
                u64 dr = (r < TROWS - 1) ? src[idx + 9] : 0;
                pR = cr | ur | dr;
            }
            u64 g = a | (a << 1) | (pL >> 63) | (a >> 1) | (pR << 63);
            dst[idx] = g & Wl[idx];
        }
        __syncthreads();
    }
    // result (after even # of iters) is in A

    // dilate horizontal: window [x-5, x+4]
    for (int idx = tid; idx < TROWS * WPR; idx += 1024) {
        int w = idx & 7;
        u64 v  = A[idx];
        u64 p  = (w > 0) ? A[idx - 1] : 0;
        u64 nx = (w < 7) ? A[idx + 1] : 0;
        u64 o = v;
#pragma unroll
        for (int d = 1; d <= 5; ++d) o |= (v << d) | (p >> (64 - d));
#pragma unroll
        for (int d = 1; d <= 4; ++d) o |= (v >> d) | (nx << (64 - d));
        B[idx] = o;
    }
    __syncthreads();

    // dilate vertical: window [y-5, y+4], zero-pad; write center 256 rows
    for (int idx = tid; idx < 256 * WPR; idx += 1024) {
        int rr = idx >> 3;
        int w  = idx & 7;
        int r  = rr + HALO;
        u64 o = 0;
#pragma unroll
        for (int dy = -5; dy <= 4; ++dy) o |= B[(r + dy) * WPR + w];
        int outrow = half * 256 + rr;
        dilBits[(size_t)n * WPI + outrow * WPR + w] = o;
    }
}

// ---- Stage E: 10x10 box blur (reflect101) from bit-packed dilated map -----
__global__ __launch_bounds__(256) void k_blur(const u64* __restrict__ dilBits,
                                              float* __restrict__ E) {
    int n  = blockIdx.y;
    int y0 = blockIdx.x * 64;
    __shared__ u64 rows[74 * WPR];
    __shared__ unsigned char rc[74 * 512];
    int tid = threadIdx.x;

    for (int idx = tid; idx < 74 * WPR; idx += 256) {
        int vi = idx >> 3;
        int w  = idx & 7;
        int v  = y0 - 5 + vi;
        int r  = v < 0 ? -v : (v > HH - 1 ? 2 * (HH - 1) - v : v);  // reflect101
        rows[idx] = dilBits[(size_t)n * WPI + r * WPR + w];
    }
    __syncthreads();

    // horizontal 10-bit window popcount per pixel (reflect101 at x edges)
    for (int idx = tid; idx < 74 * 512; idx += 256) {
        int r = idx >> 9;
        int x = idx & 511;
        int c;
        if (x >= 5 && x <= 507) {
            int b = x - 5, wd = b >> 6, off = b & 63;
            u64 v = rows[r * WPR + wd] >> off;
            if (off && wd < 7) v |= rows[r * WPR + wd + 1] << (64 - off);
            c = __popcll(v & 0x3FFull);
        } else {
            c = 0;
            for (int dx = -5; dx <= 4; ++dx) {
                int xx = x + dx;
                xx = xx < 0 ? -xx : (xx > WW - 1 ? 2 * (WW - 1) - xx : xx);
                c += (int)((rows[r * WPR + (xx >> 6)] >> (xx & 63)) & 1ull);
            }
        }
        rc[idx] = (unsigned char)c;
    }
    __syncthreads();

    // vertical sum of 10 rowcounts, then EdgeNorm quantize
    for (int idx = tid; idx < 64 * 512; idx += 256) {
        int yy = idx >> 9;
        int x  = idx & 511;
        int sum = 0;
#pragma unroll
        for (int k = 0; k < 10; ++k) sum += rc[(yy + k) * 512 + x];
        // edges are {0,255}: box sum = 255*cnt; /100, round half-even, /255
        float b = rintf((255.0f * (float)sum) / 100.0f);
        E[(size_t)n * HW + (y0 + yy) * WW + x] = b / 255.0f;
    }
}

// ---- Stage F: per-(n,c) KL partials — no max shift needed -----------------
// |e*pred| <= ~6 so exp() never overflows; Zt <= ~5e7 fits float easily.
// loss_nc = Wt/Zt - log Zt + log Zs with Zt=sum e^t, Wt=sum e^t (t-s), Zs=sum e^s
__global__ __launch_bounds__(256) void k_kl_partial(const float* __restrict__ S,
                                                    const float* __restrict__ T,
                                                    const float* __restrict__ E,
                                                    double* __restrict__ partial) {
    int cidx  = blockIdx.x;   // n*CC + c
    int split = blockIdx.y;   // 0..KSPLIT-1
    int n = cidx / CC;
    const float4* Tp = (const float4*)(T + (size_t)cidx * HW + (size_t)split * KCHUNK);
    const float4* Sp = (const float4*)(S + (size_t)cidx * HW + (size_t)split * KCHUNK);
    const float4* Ep = (const float4*)(E + (size_t)n    * HW + (size_t)split * KCHUNK);
    int tid = threadIdx.x;

    float Zt = 0.0f, Wt = 0.0f, Zs = 0.0f;
#pragma unroll
    for (int k = 0; k < KCHUNK / 4 / 256; ++k) {       // 16 iterations
        int j = k * 256 + tid;
        float4 t4 = Tp[j];
        float4 s4 = Sp[j];
        float4 e4 = Ep[j];
#pragma unroll
        for (int u = 0; u < 4; ++u) {
            float e = (&e4.x)[u];
            float t = e * (&t4.x)[u];
            float s = e * (&s4.x)[u];
            float et = __expf(t);
            Zt += et;
            Wt += et * (t - s);
            Zs += __expf(s);
        }
    }

    __shared__ double r1[256], r2[256], r3[256];
    r1[tid] = (double)Zt; r2[tid] = (double)Wt; r3[tid] = (double)Zs;
    __syncthreads();
    for (int off = 128; off > 0; off >>= 1) {
        if (tid < off) {
            r1[tid] += r1[tid + off];
            r2[tid] += r2[tid + off];
            r3[tid] += r3[tid + off];
        }
        __syncthreads();
    }
    if (tid == 0) {
        double* o = partial + ((size_t)cidx * KSPLIT + split) * 3;
        o[0] = r1[0]; o[1] = r2[0]; o[2] = r3[0];
    }
}

// ---- Stage G: final reduce -> scalar loss ---------------------------------
__global__ __launch_bounds__(128) void k_kl_final(const double* __restrict__ partial,
                                                  float* __restrict__ out) {
    int tid = threadIdx.x;
    double loss = 0.0;
    if (tid < NB * CC) {
        double Zt = 0.0, Wt = 0.0, Zs = 0.0;
        for (int sp = 0; sp < KSPLIT; ++sp) {
            const double* p = partial + ((size_t)tid * KSPLIT + sp) * 3;
            Zt += p[0]; Wt += p[1]; Zs += p[2];
        }
        loss = Wt / Zt - log(Zt) + log(Zs);
    }
    __shared__ double red[128];
    red[tid] = loss;
    __syncthreads();
    for (int off = 64; off > 0; off >>= 1) {
        if (tid < off) red[tid] += red[tid + off];
        __syncthreads();
    }
    if (tid == 0) out[0] = (float)(red[0] / (double)(NB * CC));  // T^2 = 1
}

extern "C" void kernel_launch(void* const* d_in, const int* in_sizes, int n_in,
                              void* d_out, int out_size, void* d_ws, size_t ws_size,
                              hipStream_t stream) {
    const float* S = (const float*)d_in[0];   // preds_S
    const float* T = (const float*)d_in[1];   // preds_T
    float* out = (float*)d_out;

    char* ws = (char*)d_ws;
    float*          e_buf      = (float*)(ws);                               // 8 MB
    unsigned short* m16        = (unsigned short*)(ws + (size_t)NHW * 4);    // 4 MB
    unsigned char*  tmap       = (unsigned char*)(ws + (size_t)NHW * 6);     // 2 MB
    u64*            weakBits   = (u64*)(ws + (size_t)NHW * 7);               // 256 KB
    u64*            strongBits = (u64*)(ws + (size_t)NHW * 7 + (NHW/8));     // 256 KB
    u64*            dilBits    = (u64*)(ws + (size_t)NHW * 7 + 2*(NHW/8));   // 256 KB
    double*         partial    = (double*)(ws + (size_t)NHW * 7 + 3*(NHW/8)); // 43 KB

    dim3 blk(256);
    dim3 grd(NHW / 256);

    k_argmax<<<grd, blk, 0, stream>>>(T, tmap);
    k_sobel <<<grd, blk, 0, stream>>>(tmap, m16);
    k_nms   <<<grd, blk, 0, stream>>>(m16, weakBits, strongBits);
    k_hyst_dil<<<dim3(NB * 2), dim3(1024), 0, stream>>>(strongBits, weakBits, dilBits);
    k_blur  <<<dim3(8, NB), blk, 0, stream>>>(dilBits, e_buf);
    k_kl_partial<<<dim3(NB * CC, KSPLIT), blk, 0, stream>>>(S, T, e_buf, partial);
    k_kl_final<<<1, 128, 0, stream>>>(partial, out);
    (void)in_sizes; (void)n_in; (void)out_size; (void)ws_size;
}

// Round 3
// 315.335 us; speedup vs baseline: 1.8872x; 1.1171x over previous
//
#include <hip/hip_runtime.h>
#include <math.h>

#define NB 8
#define CC 14
#define HH 512
#define WW 512
#define HW (HH*WW)          // 262144
#define NHW (NB*HW)         // 2097152
#define WPR 8               // uint64 words per row (512 bits)
#define WPI (HH*WPR)        // 4096 words per image
#define KSPLIT 32
#define KCHUNK (HW/KSPLIT)  // 8192

typedef unsigned long long u64;

// ---------------- Stage A: teacher argmax -> uint8 gray map (x4 vec) -------
__global__ __launch_bounds__(256) void k_argmax(const float* __restrict__ T,
                                                uchar4* __restrict__ tmap4) {
    int i4 = blockIdx.x * blockDim.x + threadIdx.x;     // 4-pixel group id
    if (i4 >= NHW / 4) return;
    int n  = i4 / (HW / 4);
    int p4 = i4 - n * (HW / 4);
    const float4* base = (const float4*)(T + (size_t)n * CC * HW) + p4;
    float4 best = base[0];
    int b0 = 0, b1 = 0, b2 = 0, b3 = 0;
#pragma unroll
    for (int c = 1; c < CC; ++c) {
        float4 v = base[(size_t)c * (HW / 4)];
        if (v.x > best.x) { best.x = v.x; b0 = c; }
        if (v.y > best.y) { best.y = v.y; b1 = c; }
        if (v.z > best.z) { best.z = v.z; b2 = c; }
        if (v.w > best.w) { best.w = v.w; b3 = c; }
    }
    uchar4 g;
    g.x = (unsigned char)(((float)b0 / 13.0f) * 255.0f);  // match op order: /13 then *255, trunc
    g.y = (unsigned char)(((float)b1 / 13.0f) * 255.0f);
    g.z = (unsigned char)(((float)b2 / 13.0f) * 255.0f);
    g.w = (unsigned char)(((float)b3 / 13.0f) * 255.0f);
    tmap4[i4] = g;
}

// ------- Stage B: fused Sobel(replicate) + NMS(zero-pad) -> weak/strong bits
// grid (8,8,NB): 64x64 tile per block; tm halo 2, mag/sect halo 1.
__global__ __launch_bounds__(256) void k_sobel_nms(const unsigned char* __restrict__ tmap,
                                                   u64* __restrict__ weakBits,
                                                   u64* __restrict__ strongBits) {
    int tx = blockIdx.x, ty = blockIdx.y, n = blockIdx.z;
    int x0 = tx * 64, y0 = ty * 64;
    __shared__ unsigned char tm[68 * 68];
    __shared__ unsigned short ms[66 * 66];
    int tid = threadIdx.x;
    const unsigned char* im = tmap + (size_t)n * HW;

    // phase 1: load 68x68 tmap tile, replicate-clamped at image borders
    for (int idx = tid; idx < 68 * 68; idx += 256) {
        int r = idx / 68, c = idx - r * 68;
        int yy = y0 - 2 + r; yy = yy < 0 ? 0 : (yy > HH - 1 ? HH - 1 : yy);
        int xx = x0 - 2 + c; xx = xx < 0 ? 0 : (xx > WW - 1 ? WW - 1 : xx);
        tm[idx] = im[yy * WW + xx];
    }
    __syncthreads();

    // phase 2: sobel -> (mag<<2)|sector for 66x66 (halo 1 for NMS)
    for (int idx = tid; idx < 66 * 66; idx += 256) {
        int r = idx / 66, c = idx - r * 66;
        const unsigned char* t0 = tm + r * 68 + c;   // top-left of 3x3
        int a00 = t0[0],   a01 = t0[1],   a02 = t0[2];
        int a10 = t0[68],                 a12 = t0[70];
        int a20 = t0[136], a21 = t0[137], a22 = t0[138];
        int gx = (a02 - a00) + 2 * (a12 - a10) + (a22 - a20);
        int gy = (a20 - a00) + 2 * (a21 - a01) + (a22 - a02);
        int m = (gx < 0 ? -gx : gx) + (gy < 0 ? -gy : gy);   // L1 magnitude, exact int
        float ang = atan2f((float)gy, (float)gx) * 57.29577951308232f;
        ang = fmodf(ang, 180.0f);
        if (ang < 0.0f) ang += 180.0f;
        int s;
        if (ang < 22.5f || ang >= 157.5f) s = 0;
        else if (ang < 67.5f)             s = 1;
        else if (ang < 112.5f)            s = 2;
        else                              s = 3;
        ms[idx] = (unsigned short)((m << 2) | s);
    }
    __syncthreads();

    // phase 3: NMS + ballot-pack; lane = x-in-tile (tile is one 64-bit word col)
    int lane = tid & 63;
    int warp = tid >> 6;
#pragma unroll
    for (int it = 0; it < 16; ++it) {
        int row = it * 4 + warp;
        int gy_ = y0 + row, gx_ = x0 + lane;
        int v = ms[(row + 1) * 66 + (lane + 1)];
        int mc = v >> 2, s = v & 3;
        int dy1, dx1, dy2, dx2;
        if (s == 0)      { dy1 = 0;  dx1 = 1;  dy2 = 0; dx2 = -1; }
        else if (s == 1) { dy1 = -1; dx1 = 1;  dy2 = 1; dx2 = -1; }
        else if (s == 2) { dy1 = -1; dx1 = 0;  dy2 = 1; dx2 = 0;  }
        else             { dy1 = -1; dx1 = -1; dy2 = 1; dx2 = 1;  }
        int y1 = gy_ + dy1, x1 = gx_ + dx1, y2 = gy_ + dy2, x2 = gx_ + dx2;
        int n1 = (y1 < 0 || y1 >= HH || x1 < 0 || x1 >= WW)
                 ? 0 : (ms[(row + 1 + dy1) * 66 + (lane + 1 + dx1)] >> 2);
        int n2 = (y2 < 0 || y2 >= HH || x2 < 0 || x2 >= WW)
                 ? 0 : (ms[(row + 1 + dy2) * 66 + (lane + 1 + dx2)] >> 2);
        int nms = (mc >= n1 && mc >= n2) ? mc : 0;
        u64 wm = __ballot(nms > 10);
        u64 sm = __ballot(nms > 50);
        if (lane == 0) {
            size_t w = (size_t)n * WPI + gy_ * WPR + tx;
            weakBits[w]   = wm;
            strongBits[w] = sm;
        }
    }
}

// ---- Stage C+D: 16 hysteresis iterations + 10x10 dilate, bit-packed -------
// 8 tiles/image (64 rows each) + 21-row halo: 16 grow iters contaminate 16
// rows from the unknown tile edge, dilate needs 5 more -> 21 is exact.
#define HALO 21
#define TROWS (64 + 2*HALO)    // 106
#define TWORDS (TROWS * WPR)   // 848
__global__ __launch_bounds__(1024) void k_hyst_dil(const u64* __restrict__ strongBits,
                                                   const u64* __restrict__ weakBits,
                                                   u64* __restrict__ dilBits) {
    int tile = blockIdx.x & 7;
    int n    = blockIdx.x >> 3;
    int g0   = tile * 64 - HALO;           // virtual first row of tile
    __shared__ u64 A[TWORDS];
    __shared__ u64 B[TWORDS];
    __shared__ u64 Wl[TWORDS];
    int tid = threadIdx.x;

    if (tid < TWORDS) {
        int vr = g0 + (tid >> 3);
        int w  = tid & 7;
        u64 sv = 0, wv = 0;
        if (vr >= 0 && vr < HH) {
            sv = strongBits[(size_t)n * WPI + vr * WPR + w];
            wv = weakBits  [(size_t)n * WPI + vr * WPR + w];
        }
        A[tid] = sv;
        Wl[tid] = wv;
    }
    __syncthreads();

#pragma unroll 1
    for (int it = 0; it < 16; ++it) {
        const u64* src = (it & 1) ? B : A;
        u64*       dst = (it & 1) ? A : B;
        if (tid < TWORDS) {
            int r = tid >> 3;
            int w = tid & 7;
            u64 c  = src[tid];
            u64 up = (r > 0)         ? src[tid - 8] : 0;
            u64 dn = (r < TROWS - 1) ? src[tid + 8] : 0;
            u64 a = c | up | dn;
            u64 pL = 0, pR = 0;
            if (w > 0) {
                u64 cl = src[tid - 1];
                u64 ul = (r > 0)         ? src[tid - 9] : 0;
                u64 dl = (r < TROWS - 1) ? src[tid + 7] : 0;
                pL = cl | ul | dl;
            }
            if (w < 7) {
                u64 cr = src[tid + 1];
                u64 ur = (r > 0)         ? src[tid - 7] : 0;
                u64 dr = (r < TROWS - 1) ? src[tid + 9] : 0;
                pR = cr | ur | dr;
            }
            u64 g = a | (a << 1) | (pL >> 63) | (a >> 1) | (pR << 63);
            dst[tid] = g & Wl[tid];
        }
        __syncthreads();
    }
    // result (after 16 iters) is in A

    // dilate horizontal: window [x-5, x+4]
    if (tid < TWORDS) {
        int w = tid & 7;
        u64 v  = A[tid];
        u64 p  = (w > 0) ? A[tid - 1] : 0;
        u64 nx = (w < 7) ? A[tid + 1] : 0;
        u64 o = v;
#pragma unroll
        for (int d = 1; d <= 5; ++d) o |= (v << d) | (p >> (64 - d));
#pragma unroll
        for (int d = 1; d <= 4; ++d) o |= (v >> d) | (nx << (64 - d));
        B[tid] = o;
    }
    __syncthreads();

    // dilate vertical: window [y-5, y+4], zero-pad; write center 64 rows
    if (tid < 64 * WPR) {
        int rr = tid >> 3;
        int w  = tid & 7;
        int r  = rr + HALO;
        u64 o = 0;
#pragma unroll
        for (int dy = -5; dy <= 4; ++dy) o |= B[(r + dy) * WPR + w];
        dilBits[(size_t)n * WPI + (tile * 64 + rr) * WPR + w] = o;
    }
}

// ---- Stage E: 10x10 box blur (reflect101) from bit-packed dilated map -----
// grid (16, NB): 32-row tiles; vertical pass = exact integer rolling window.
__global__ __launch_bounds__(256) void k_blur(const u64* __restrict__ dilBits,
                                              float* __restrict__ E) {
    int n  = blockIdx.y;
    int y0 = blockIdx.x * 32;
    __shared__ u64 rows[42 * WPR];
    __shared__ unsigned char rc[42 * 512];
    int tid = threadIdx.x;

    for (int idx = tid; idx < 42 * WPR; idx += 256) {
        int vi = idx >> 3;
        int w  = idx & 7;
        int v  = y0 - 5 + vi;
        int r  = v < 0 ? -v : (v > HH - 1 ? 2 * (HH - 1) - v : v);  // reflect101
        rows[idx] = dilBits[(size_t)n * WPI + r * WPR + w];
    }
    __syncthreads();

    // horizontal 10-bit window popcount per pixel (reflect101 at x edges)
    for (int idx = tid; idx < 42 * 512; idx += 256) {
        int r = idx >> 9;
        int x = idx & 511;
        int c;
        if (x >= 5 && x <= 507) {
            int b = x - 5, wd = b >> 6, off = b & 63;
            u64 v = rows[r * WPR + wd] >> off;
            if (off && wd < 7) v |= rows[r * WPR + wd + 1] << (64 - off);
            c = __popcll(v & 0x3FFull);
        } else {
            c = 0;
            for (int dx = -5; dx <= 4; ++dx) {
                int xx = x + dx;
                xx = xx < 0 ? -xx : (xx > WW - 1 ? 2 * (WW - 1) - xx : xx);
                c += (int)((rows[r * WPR + (xx >> 6)] >> (xx & 63)) & 1ull);
            }
        }
        rc[idx] = (unsigned char)c;
    }
    __syncthreads();

    // vertical rolling sum of 10 rowcounts; thread owns 2 columns
    for (int x = tid; x < 512; x += 256) {
        int sum = 0;
#pragma unroll
        for (int k = 0; k < 10; ++k) sum += rc[k * 512 + x];
        float* o = E + (size_t)n * HW + y0 * WW + x;
        // edges are {0,255}: box sum = 255*cnt; /100, round half-even, /255
        o[0] = rintf((255.0f * (float)sum) / 100.0f) / 255.0f;
        for (int yy = 1; yy < 32; ++yy) {
            sum += (int)rc[(yy + 9) * 512 + x] - (int)rc[(yy - 1) * 512 + x];
            o[yy * WW] = rintf((255.0f * (float)sum) / 100.0f) / 255.0f;
        }
    }
}

// ---- Stage F: per-(n,c) KL partials — no max shift needed -----------------
// |e*pred| <= ~6 so exp() never overflows; Z <= ~5e7 fits float easily.
// loss_nc = Wt/Zt - log Zt + log Zs with Zt=sum e^t, Wt=sum e^t (t-s), Zs=sum e^s
__global__ __launch_bounds__(256) void k_kl_partial(const float* __restrict__ S,
                                                    const float* __restrict__ T,
                                                    const float* __restrict__ E,
                                                    double* __restrict__ partial) {
    int cidx  = blockIdx.x;   // n*CC + c
    int split = blockIdx.y;   // 0..KSPLIT-1
    int n = cidx / CC;
    const float4* Tp = (const float4*)(T + (size_t)cidx * HW + (size_t)split * KCHUNK);
    const float4* Sp = (const float4*)(S + (size_t)cidx * HW + (size_t)split * KCHUNK);
    const float4* Ep = (const float4*)(E + (size_t)n    * HW + (size_t)split * KCHUNK);
    int tid = threadIdx.x;

    float Zt = 0.0f, Wt = 0.0f, Zs = 0.0f;
#pragma unroll
    for (int k = 0; k < KCHUNK / 4 / 256; ++k) {       // 8 iterations
        int j = k * 256 + tid;
        float4 t4 = Tp[j];
        float4 s4 = Sp[j];
        float4 e4 = Ep[j];
#pragma unroll
        for (int u = 0; u < 4; ++u) {
            float e = (&e4.x)[u];
            float t = e * (&t4.x)[u];
            float s = e * (&s4.x)[u];
            float et = __expf(t);
            Zt += et;
            Wt += et * (t - s);
            Zs += __expf(s);
        }
    }

    __shared__ double r1[256], r2[256], r3[256];
    r1[tid] = (double)Zt; r2[tid] = (double)Wt; r3[tid] = (double)Zs;
    __syncthreads();
    for (int off = 128; off > 0; off >>= 1) {
        if (tid < off) {
            r1[tid] += r1[tid + off];
            r2[tid] += r2[tid + off];
            r3[tid] += r3[tid + off];
        }
        __syncthreads();
    }
    if (tid == 0) {
        double* o = partial + ((size_t)cidx * KSPLIT + split) * 3;
        o[0] = r1[0]; o[1] = r2[0]; o[2] = r3[0];
    }
}

// ---- Stage G: final reduce -> scalar loss ---------------------------------
__global__ __launch_bounds__(128) void k_kl_final(const double* __restrict__ partial,
                                                  float* __restrict__ out) {
    int tid = threadIdx.x;
    double loss = 0.0;
    if (tid < NB * CC) {
        double Zt = 0.0, Wt = 0.0, Zs = 0.0;
        for (int sp = 0; sp < KSPLIT; ++sp) {
            const double* p = partial + ((size_t)tid * KSPLIT + sp) * 3;
            Zt += p[0]; Wt += p[1]; Zs += p[2];
        }
        loss = Wt / Zt - log(Zt) + log(Zs);
    }
    __shared__ double red[128];
    red[tid] = loss;
    __syncthreads();
    for (int off = 64; off > 0; off >>= 1) {
        if (tid < off) red[tid] += red[tid + off];
        __syncthreads();
    }
    if (tid == 0) out[0] = (float)(red[0] / (double)(NB * CC));  // T^2 = 1
}

extern "C" void kernel_launch(void* const* d_in, const int* in_sizes, int n_in,
                              void* d_out, int out_size, void* d_ws, size_t ws_size,
                              hipStream_t stream) {
    const float* S = (const float*)d_in[0];   // preds_S
    const float* T = (const float*)d_in[1];   // preds_T
    float* out = (float*)d_out;

    char* ws = (char*)d_ws;
    float*         e_buf      = (float*)(ws);                               // 8 MB
    unsigned char* tmap       = (unsigned char*)(ws + (size_t)NHW * 4);     // 2 MB
    u64*           weakBits   = (u64*)(ws + (size_t)NHW * 5);               // 256 KB
    u64*           strongBits = (u64*)(ws + (size_t)NHW * 5 + (NHW/8));     // 256 KB
    u64*           dilBits    = (u64*)(ws + (size_t)NHW * 5 + 2*(NHW/8));   // 256 KB
    double*        partial    = (double*)(ws + (size_t)NHW * 5 + 3*(NHW/8)); // 86 KB

    k_argmax<<<dim3(NHW / 4 / 256), dim3(256), 0, stream>>>(T, (uchar4*)tmap);
    k_sobel_nms<<<dim3(8, 8, NB), dim3(256), 0, stream>>>(tmap, weakBits, strongBits);
    k_hyst_dil<<<dim3(NB * 8), dim3(1024), 0, stream>>>(strongBits, weakBits, dilBits);
    k_blur<<<dim3(16, NB), dim3(256), 0, stream>>>(dilBits, e_buf);
    k_kl_partial<<<dim3(NB * CC, KSPLIT), dim3(256), 0, stream>>>(S, T, e_buf, partial);
    k_kl_final<<<1, 128, 0, stream>>>(partial, out);
    (void)in_sizes; (void)n_in; (void)out_size; (void)ws_size;
}

// Round 4
// 301.387 us; speedup vs baseline: 1.9746x; 1.0463x over previous
//
#include <hip/hip_runtime.h>
#include <math.h>

#define NB 8
#define CC 14
#define HH 512
#define WW 512
#define HW (HH*WW)          // 262144
#define NHW (NB*HW)         // 2097152
#define WPR 8               // uint64 words per row (512 bits)
#define WPI (HH*WPR)        // 4096 words per image
#define KSPLIT 32
#define KCHUNK (HW/KSPLIT)  // 8192

typedef unsigned long long u64;

// ---------------- Stage A: teacher argmax -> uint8 gray map (x4 vec) -------
__global__ __launch_bounds__(256) void k_argmax(const float* __restrict__ T,
                                                uchar4* __restrict__ tmap4) {
    int i4 = blockIdx.x * blockDim.x + threadIdx.x;     // 4-pixel group id
    if (i4 >= NHW / 4) return;
    int n  = i4 / (HW / 4);
    int p4 = i4 - n * (HW / 4);
    const float4* base = (const float4*)(T + (size_t)n * CC * HW) + p4;
    float4 best = base[0];
    int b0 = 0, b1 = 0, b2 = 0, b3 = 0;
#pragma unroll
    for (int c = 1; c < CC; ++c) {
        float4 v = base[(size_t)c * (HW / 4)];
        if (v.x > best.x) { best.x = v.x; b0 = c; }
        if (v.y > best.y) { best.y = v.y; b1 = c; }
        if (v.z > best.z) { best.z = v.z; b2 = c; }
        if (v.w > best.w) { best.w = v.w; b3 = c; }
    }
    uchar4 g;
    g.x = (unsigned char)(((float)b0 / 13.0f) * 255.0f);  // match op order: /13 then *255, trunc
    g.y = (unsigned char)(((float)b1 / 13.0f) * 255.0f);
    g.z = (unsigned char)(((float)b2 / 13.0f) * 255.0f);
    g.w = (unsigned char)(((float)b3 / 13.0f) * 255.0f);
    tmap4[i4] = g;
}

// ------- Stage B: fused Sobel(replicate) + NMS(zero-pad) -> weak/strong bits
// grid (8,8,NB): 64x64 tile per block; tm halo 2, mag/sect halo 1.
__global__ __launch_bounds__(256) void k_sobel_nms(const unsigned char* __restrict__ tmap,
                                                   u64* __restrict__ weakBits,
                                                   u64* __restrict__ strongBits) {
    int tx = blockIdx.x, ty = blockIdx.y, n = blockIdx.z;
    int x0 = tx * 64, y0 = ty * 64;
    __shared__ unsigned char tm[68 * 68];
    __shared__ unsigned short ms[66 * 66];
    int tid = threadIdx.x;
    const unsigned char* im = tmap + (size_t)n * HW;

    // phase 1: load 68x68 tmap tile, replicate-clamped at image borders
    for (int idx = tid; idx < 68 * 68; idx += 256) {
        int r = idx / 68, c = idx - r * 68;
        int yy = y0 - 2 + r; yy = yy < 0 ? 0 : (yy > HH - 1 ? HH - 1 : yy);
        int xx = x0 - 2 + c; xx = xx < 0 ? 0 : (xx > WW - 1 ? WW - 1 : xx);
        tm[idx] = im[yy * WW + xx];
    }
    __syncthreads();

    // phase 2: sobel -> (mag<<2)|sector for 66x66 (halo 1 for NMS)
    for (int idx = tid; idx < 66 * 66; idx += 256) {
        int r = idx / 66, c = idx - r * 66;
        const unsigned char* t0 = tm + r * 68 + c;   // top-left of 3x3
        int a00 = t0[0],   a01 = t0[1],   a02 = t0[2];
        int a10 = t0[68],                 a12 = t0[70];
        int a20 = t0[136], a21 = t0[137], a22 = t0[138];
        int gx = (a02 - a00) + 2 * (a12 - a10) + (a22 - a20);
        int gy = (a20 - a00) + 2 * (a21 - a01) + (a22 - a02);
        int m = (gx < 0 ? -gx : gx) + (gy < 0 ? -gy : gy);   // L1 magnitude, exact int
        float ang = atan2f((float)gy, (float)gx) * 57.29577951308232f;
        ang = fmodf(ang, 180.0f);
        if (ang < 0.0f) ang += 180.0f;
        int s;
        if (ang < 22.5f || ang >= 157.5f) s = 0;
        else if (ang < 67.5f)             s = 1;
        else if (ang < 112.5f)            s = 2;
        else                              s = 3;
        ms[idx] = (unsigned short)((m << 2) | s);
    }
    __syncthreads();

    // phase 3: NMS + ballot-pack; lane = x-in-tile (tile is one 64-bit word col)
    int lane = tid & 63;
    int warp = tid >> 6;
#pragma unroll
    for (int it = 0; it < 16; ++it) {
        int row = it * 4 + warp;
        int gy_ = y0 + row, gx_ = x0 + lane;
        int v = ms[(row + 1) * 66 + (lane + 1)];
        int mc = v >> 2, s = v & 3;
        int dy1, dx1, dy2, dx2;
        if (s == 0)      { dy1 = 0;  dx1 = 1;  dy2 = 0; dx2 = -1; }
        else if (s == 1) { dy1 = -1; dx1 = 1;  dy2 = 1; dx2 = -1; }
        else if (s == 2) { dy1 = -1; dx1 = 0;  dy2 = 1; dx2 = 0;  }
        else             { dy1 = -1; dx1 = -1; dy2 = 1; dx2 = 1;  }
        int y1 = gy_ + dy1, x1 = gx_ + dx1, y2 = gy_ + dy2, x2 = gx_ + dx2;
        int n1 = (y1 < 0 || y1 >= HH || x1 < 0 || x1 >= WW)
                 ? 0 : (ms[(row + 1 + dy1) * 66 + (lane + 1 + dx1)] >> 2);
        int n2 = (y2 < 0 || y2 >= HH || x2 < 0 || x2 >= WW)
                 ? 0 : (ms[(row + 1 + dy2) * 66 + (lane + 1 + dx2)] >> 2);
        int nms = (mc >= n1 && mc >= n2) ? mc : 0;
        u64 wm = __ballot(nms > 10);
        u64 sm = __ballot(nms > 50);
        if (lane == 0) {
            size_t w = (size_t)n * WPI + gy_ * WPR + tx;
            weakBits[w]   = wm;
            strongBits[w] = sm;
        }
    }
}

// ---- Stage C+D+E: 16 hysteresis iters + 10x10 dilate + 10x10 blur, fused --
// 8 tiles/image (64 rows each) + 26-row halo. Exactness: 16 grow iters
// contaminate 16 rows from the unknown tile edge -> A exact on local rows
// [16, 99]; vertical dilate row d (d in [0,73], global t64-5+d) reads
// horizontally-dilated B rows [d+16, d+25] in [16,99] -> exact. Blur of the
// 64 output rows needs exactly dil rows global [t64-5, t64+68] (with
// reflect101 at image borders mapping back inside this range).
#define HALO 26
#define TROWS (64 + 2*HALO)    // 116
#define TWORDS (TROWS * WPR)   // 928
__global__ __launch_bounds__(1024) void k_hyst_dil_blur(const u64* __restrict__ strongBits,
                                                        const u64* __restrict__ weakBits,
                                                        float* __restrict__ E) {
    int tile = blockIdx.x & 7;
    int n    = blockIdx.x >> 3;
    int t64  = tile * 64;
    int g0   = t64 - HALO;                 // virtual first row of tile
    __shared__ u64 A[TWORDS];
    __shared__ u64 B[TWORDS];
    __shared__ u64 Wl[TWORDS];             // weak bits; reused as D (dilated) later
    __shared__ unsigned char rc[74 * 512]; // horizontal blur rowcounts
    int tid = threadIdx.x;

    if (tid < TWORDS) {
        int vr = g0 + (tid >> 3);
        int w  = tid & 7;
        u64 sv = 0, wv = 0;
        if (vr >= 0 && vr < HH) {
            sv = strongBits[(size_t)n * WPI + vr * WPR + w];
            wv = weakBits  [(size_t)n * WPI + vr * WPR + w];
        }
        A[tid] = sv;
        Wl[tid] = wv;
    }
    __syncthreads();

#pragma unroll 1
    for (int it = 0; it < 16; ++it) {
        const u64* src = (it & 1) ? B : A;
        u64*       dst = (it & 1) ? A : B;
        if (tid < TWORDS) {
            int r = tid >> 3;
            int w = tid & 7;
            u64 c  = src[tid];
            u64 up = (r > 0)         ? src[tid - 8] : 0;
            u64 dn = (r < TROWS - 1) ? src[tid + 8] : 0;
            u64 a = c | up | dn;
            u64 pL = 0, pR = 0;
            if (w > 0) {
                u64 cl = src[tid - 1];
                u64 ul = (r > 0)         ? src[tid - 9] : 0;
                u64 dl = (r < TROWS - 1) ? src[tid + 7] : 0;
                pL = cl | ul | dl;
            }
            if (w < 7) {
                u64 cr = src[tid + 1];
                u64 ur = (r > 0)         ? src[tid - 7] : 0;
                u64 dr = (r < TROWS - 1) ? src[tid + 9] : 0;
                pR = cr | ur | dr;
            }
            u64 g = a | (a << 1) | (pL >> 63) | (a >> 1) | (pR << 63);
            dst[tid] = g & Wl[tid];
        }
        __syncthreads();
    }
    // result (after 16 iters) is in A

    // dilate horizontal: window [x-5, x+4]
    if (tid < TWORDS) {
        int w = tid & 7;
        u64 v  = A[tid];
        u64 p  = (w > 0) ? A[tid - 1] : 0;
        u64 nx = (w < 7) ? A[tid + 1] : 0;
        u64 o = v;
#pragma unroll
        for (int d = 1; d <= 5; ++d) o |= (v << d) | (p >> (64 - d));
#pragma unroll
        for (int d = 1; d <= 4; ++d) o |= (v >> d) | (nx << (64 - d));
        B[tid] = o;
    }
    __syncthreads();

    // dilate vertical: window [y-5, y+4], zero-pad beyond image (A/B are 0
    // there). D row d (d in [0,74)) = dil at global row t64-5+d = local d+21.
    u64* D = Wl;   // weak bits dead now; reuse
    if (tid < 74 * WPR) {
        int d = tid >> 3;
        int w = tid & 7;
        int r = d + 21;
        u64 o = 0;
#pragma unroll
        for (int dy = -5; dy <= 4; ++dy) o |= B[(r + dy) * WPR + w];
        D[d * WPR + w] = o;
    }
    __syncthreads();

    // horizontal 10-bit window popcount per pixel (reflect101 at x edges)
    for (int idx = tid; idx < 74 * 512; idx += 1024) {
        int r = idx >> 9;
        int x = idx & 511;
        int c;
        if (x >= 5 && x <= 507) {
            int b = x - 5, wd = b >> 6, off = b & 63;
            u64 v = D[r * WPR + wd] >> off;
            if (off && wd < 7) v |= D[r * WPR + wd + 1] << (64 - off);
            c = __popcll(v & 0x3FFull);
        } else {
            c = 0;
            for (int dx = -5; dx <= 4; ++dx) {
                int xx = x + dx;
                xx = xx < 0 ? -xx : (xx > WW - 1 ? 2 * (WW - 1) - xx : xx);
                c += (int)((D[r * WPR + (xx >> 6)] >> (xx & 63)) & 1ull);
            }
        }
        rc[idx] = (unsigned char)c;
    }
    __syncthreads();

    // vertical 10-row sum (reflect101 rows at image borders), quantize, store
    for (int idx = tid; idx < 64 * 512; idx += 1024) {
        int yy = idx >> 9;
        int x  = idx & 511;
        int gy = t64 + yy;
        int sum = 0;
        if (gy >= 5 && gy <= HH - 5) {          // window fully inside image
#pragma unroll
            for (int k = 0; k < 10; ++k) sum += rc[(yy + k) * 512 + x];
        } else {
#pragma unroll
            for (int k = 0; k < 10; ++k) {
                int v  = gy - 5 + k;
                int rv = v < 0 ? -v : (v > HH - 1 ? 2 * (HH - 1) - v : v);
                sum += rc[(rv - (t64 - 5)) * 512 + x];
            }
        }
        // edges are {0,255}: box sum = 255*cnt; /100, round half-even, /255
        float b = rintf((255.0f * (float)sum) / 100.0f);
        E[(size_t)n * HW + gy * WW + x] = b / 255.0f;
    }
}

// ---- Stage F: per-(n,c) KL partials — no max shift needed -----------------
// |e*pred| <= ~6 so exp() never overflows; Z <= ~5e7 fits float easily.
// loss_nc = Wt/Zt - log Zt + log Zs with Zt=sum e^t, Wt=sum e^t (t-s), Zs=sum e^s
__global__ __launch_bounds__(256) void k_kl_partial(const float* __restrict__ S,
                                                    const float* __restrict__ T,
                                                    const float* __restrict__ E,
                                                    double* __restrict__ partial) {
    int cidx  = blockIdx.x;   // n*CC + c
    int split = blockIdx.y;   // 0..KSPLIT-1
    int n = cidx / CC;
    const float4* Tp = (const float4*)(T + (size_t)cidx * HW + (size_t)split * KCHUNK);
    const float4* Sp = (const float4*)(S + (size_t)cidx * HW + (size_t)split * KCHUNK);
    const float4* Ep = (const float4*)(E + (size_t)n    * HW + (size_t)split * KCHUNK);
    int tid = threadIdx.x;

    float Zt = 0.0f, Wt = 0.0f, Zs = 0.0f;
#pragma unroll
    for (int k = 0; k < KCHUNK / 4 / 256; ++k) {       // 8 iterations
        int j = k * 256 + tid;
        float4 t4 = Tp[j];
        float4 s4 = Sp[j];
        float4 e4 = Ep[j];
#pragma unroll
        for (int u = 0; u < 4; ++u) {
            float e = (&e4.x)[u];
            float t = e * (&t4.x)[u];
            float s = e * (&s4.x)[u];
            float et = __expf(t);
            Zt += et;
            Wt += et * (t - s);
            Zs += __expf(s);
        }
    }

    __shared__ double r1[256], r2[256], r3[256];
    r1[tid] = (double)Zt; r2[tid] = (double)Wt; r3[tid] = (double)Zs;
    __syncthreads();
    for (int off = 128; off > 0; off >>= 1) {
        if (tid < off) {
            r1[tid] += r1[tid + off];
            r2[tid] += r2[tid + off];
            r3[tid] += r3[tid + off];
        }
        __syncthreads();
    }
    if (tid == 0) {
        double* o = partial + ((size_t)cidx * KSPLIT + split) * 3;
        o[0] = r1[0]; o[1] = r2[0]; o[2] = r3[0];
    }
}

// ---- Stage G: final reduce -> scalar loss ---------------------------------
__global__ __launch_bounds__(128) void k_kl_final(const double* __restrict__ partial,
                                                  float* __restrict__ out) {
    int tid = threadIdx.x;
    double loss = 0.0;
    if (tid < NB * CC) {
        double Zt = 0.0, Wt = 0.0, Zs = 0.0;
        for (int sp = 0; sp < KSPLIT; ++sp) {
            const double* p = partial + ((size_t)tid * KSPLIT + sp) * 3;
            Zt += p[0]; Wt += p[1]; Zs += p[2];
        }
        loss = Wt / Zt - log(Zt) + log(Zs);
    }
    __shared__ double red[128];
    red[tid] = loss;
    __syncthreads();
    for (int off = 64; off > 0; off >>= 1) {
        if (tid < off) red[tid] += red[tid + off];
        __syncthreads();
    }
    if (tid == 0) out[0] = (float)(red[0] / (double)(NB * CC));  // T^2 = 1
}

extern "C" void kernel_launch(void* const* d_in, const int* in_sizes, int n_in,
                              void* d_out, int out_size, void* d_ws, size_t ws_size,
                              hipStream_t stream) {
    const float* S = (const float*)d_in[0];   // preds_S
    const float* T = (const float*)d_in[1];   // preds_T
    float* out = (float*)d_out;

    char* ws = (char*)d_ws;
    float*         e_buf      = (float*)(ws);                               // 8 MB
    unsigned char* tmap       = (unsigned char*)(ws + (size_t)NHW * 4);     // 2 MB
    u64*           weakBits   = (u64*)(ws + (size_t)NHW * 5);               // 256 KB
    u64*           strongBits = (u64*)(ws + (size_t)NHW * 5 + (NHW/8));     // 256 KB
    double*        partial    = (double*)(ws + (size_t)NHW * 5 + 2*(NHW/8)); // 86 KB

    k_argmax<<<dim3(NHW / 4 / 256), dim3(256), 0, stream>>>(T, (uchar4*)tmap);
    k_sobel_nms<<<dim3(8, 8, NB), dim3(256), 0, stream>>>(tmap, weakBits, strongBits);
    k_hyst_dil_blur<<<dim3(NB * 8), dim3(1024), 0, stream>>>(strongBits, weakBits, e_buf);
    k_kl_partial<<<dim3(NB * CC, KSPLIT), dim3(256), 0, stream>>>(S, T, e_buf, partial);
    k_kl_final<<<1, 128, 0, stream>>>(partial, out);
    (void)in_sizes; (void)n_in; (void)out_size; (void)ws_size;
}